// Round 3
// baseline (173.448 us; speedup 1.0000x reference)
//
#include <hip/hip_runtime.h>
#include <hip/hip_bf16.h>
#include <math.h>

typedef unsigned short u16;
typedef unsigned int u32;
typedef __attribute__((ext_vector_type(4))) float f32x4;
typedef __attribute__((ext_vector_type(8))) __bf16 bf16x8;

// ---------------------------------------------------------------- fp32 -> bf16
__device__ __forceinline__ u16 f2bf(float x) {
    unsigned u = __float_as_uint(x);
    u += 0x7fffu + ((u >> 16) & 1u);   // round-to-nearest-even
    return (u16)(u >> 16);
}
__device__ __forceinline__ unsigned pk(float lo, float hi) {
    return (unsigned)f2bf(lo) | ((unsigned)f2bf(hi) << 16);
}

__global__ void cvt_bf16(const float* __restrict__ s, u16* __restrict__ d, int n) {
    int i = (blockIdx.x * blockDim.x + threadIdx.x) * 8;
    if (i >= n) return;
    float4 v0 = *(const float4*)(s + i);
    float4 v1 = *(const float4*)(s + i + 4);
    uint4 o;
    o.x = pk(v0.x, v0.y); o.y = pk(v0.z, v0.w);
    o.z = pk(v1.x, v1.y); o.w = pk(v1.z, v1.w);
    *(uint4*)(d + i) = o;
}

// ---------------------------------------------------------------- GEMM + max
#define GLB_AS __attribute__((address_space(1)))
#define LDS_AS __attribute__((address_space(3)))

__device__ __forceinline__ void gload_lds16(const void* g, void* l) {
    __builtin_amdgcn_global_load_lds((const GLB_AS void*)g, (LDS_AS void*)l, 16, 0, 0);
}

// A: F bf16 [1024 x 512], B: T bf16 [32768 x 512] (row-major, K contiguous)
// sim[i*1024 + j] = max_{q<32} dot(A[i], B[j*32+q]) / temp
// LDS layout XOR-swizzled at 16B granularity: chunk (row, c) lives at 16B-slot
// row*4 + (c ^ (row&3)).  Staging picks global chunk c = (l&3)^((l>>2)&3) so the
// wave-uniform-base+lane*16 constraint of global_load_lds realizes the swizzle.
__global__ __launch_bounds__(256, 2)
void gemm_max(const u16* __restrict__ A, const u16* __restrict__ B,
              const float* __restrict__ temp_ptr, float* __restrict__ sim) {
    __shared__ __align__(16) u16 lA[128 * 32];
    __shared__ __align__(16) u16 lB[128 * 32];
    const int bn = blockIdx.x;      // 0..255 (N tiles of 128 = 4 j's)
    const int bm = blockIdx.y;      // 0..7   (M tiles of 128)
    const int tid  = threadIdx.x;
    const int wave = tid >> 6;      // 0..3
    const int lane = tid & 63;
    const int wm = wave >> 1;       // 0..1
    const int wn = wave & 1;        // 0..1

    f32x4 acc[4][4] = {};

    const int rA = lane >> 2;                                  // row within 16-row group
    const int kc = (((lane & 3) ^ ((lane >> 2) & 3)) << 3);    // swizzled k-chunk (elems)
    const u16* gA = A + (size_t)(bm * 128 + wave * 16 + rA) * 512 + kc;
    const u16* gB = B + (size_t)(bn * 128 + wave * 16 + rA) * 512 + kc;
    u16* dA = lA + wave * 512;
    u16* dB = lB + wave * 512;

    const int frow = lane & 15;
    const int fq   = lane >> 4;                 // k-quad 0..3
    const int fsw  = (fq ^ (frow & 3)) << 3;    // swizzled read chunk (elems)

    for (int k0 = 0; k0 < 512; k0 += 32) {
        gload_lds16(gA + k0,            dA);
        gload_lds16(gA + k0 + 64 * 512, dA + 2048);
        gload_lds16(gB + k0,            dB);
        gload_lds16(gB + k0 + 64 * 512, dB + 2048);
        __syncthreads();

        bf16x8 af[4], bf[4];
#pragma unroll
        for (int t = 0; t < 4; ++t) {
            af[t] = *(const bf16x8*)&lA[(wm * 64 + t * 16 + frow) * 32 + fsw];
            bf[t] = *(const bf16x8*)&lB[(wn * 64 + t * 16 + frow) * 32 + fsw];
        }
#pragma unroll
        for (int mt = 0; mt < 4; ++mt)
#pragma unroll
            for (int nt = 0; nt < 4; ++nt)
                acc[mt][nt] = __builtin_amdgcn_mfma_f32_16x16x32_bf16(
                    af[mt], bf[nt], acc[mt][nt], 0, 0, 0);
        __syncthreads();
    }

    const float tempv = *temp_ptr;
    const int quad = lane >> 4;
    const int jb = (bn * 128 + wn * 64) >> 5;
#pragma unroll
    for (int mt = 0; mt < 4; ++mt) {
#pragma unroll
        for (int rr = 0; rr < 4; ++rr) {
            float v0 = fmaxf(acc[mt][0][rr], acc[mt][1][rr]);
            float v1 = fmaxf(acc[mt][2][rr], acc[mt][3][rr]);
#pragma unroll
            for (int off = 1; off < 16; off <<= 1) {
                v0 = fmaxf(v0, __shfl_xor(v0, off));
                v1 = fmaxf(v1, __shfl_xor(v1, off));
            }
            if ((lane & 15) == 0) {
                const int row = bm * 128 + wm * 64 + mt * 16 + quad * 4 + rr;
                sim[row * 1024 + jb]     = v0 / tempv;
                sim[row * 1024 + jb + 1] = v1 / tempv;
            }
        }
    }
}

// ---------------------------------------------------------------- per-row loss
// ONE WAVE PER ROW, no __syncthreads. Row (1024 fp32) in 16 regs/lane.
// NOTE: no dynamic indexing of v[]/k[] anywhere — a runtime subscript would
// force the arrays to scratch (global-backed) memory.
__device__ __forceinline__ u32 f2key(float x) {
    u32 b = __float_as_uint(x);
    return (b & 0x80000000u) ? ~b : (b | 0x80000000u);
}
__device__ __forceinline__ float key2f(u32 k) {
    return __uint_as_float((k & 0x80000000u) ? (k & 0x7fffffffu) : ~k);
}

__global__ __launch_bounds__(256)
void row_loss(const float* __restrict__ sim, float* __restrict__ out) {
    __shared__ u32 hist[4 * 256];
    const int tid = threadIdx.x;
    const int lane = tid & 63;
    const int wv = tid >> 6;
    const int i = blockIdx.x * 4 + wv;          // row index
    u32* h = hist + wv * 256;

    // load row: slot t -> element (t>>2)*256 + lane*4 + (t&3)
    float v[16];
    const float4* rp = (const float4*)(sim + (size_t)i * 1024);
#pragma unroll
    for (int t = 0; t < 4; ++t) {
        float4 f = rp[t * 64 + lane];
        v[t * 4 + 0] = f.x; v[t * 4 + 1] = f.y; v[t * 4 + 2] = f.z; v[t * 4 + 3] = f.w;
    }

    const int dslot = ((i >> 8) << 2) | (i & 3);
    const int dlane = (i >> 2) & 63;

    // keys, with diagonal masked to key 0 (below any finite key) — constant idx only
    u32 k[16];
#pragma unroll
    for (int t = 0; t < 16; ++t) {
        u32 kk = f2key(v[t]);
        k[t] = (lane == dlane && t == dslot) ? 0u : kk;
    }

    // pos = v[dslot] at lane dlane, without dynamic register indexing
    float pv = 0.f;
#pragma unroll
    for (int t = 0; t < 16; ++t) if (t == dslot) pv = v[t];
    const float pos = __shfl(pv, dlane);

    // full-row max + logsumexp (includes diagonal)
    float m = v[0];
#pragma unroll
    for (int t = 1; t < 16; ++t) m = fmaxf(m, v[t]);
#pragma unroll
    for (int off = 32; off > 0; off >>= 1) m = fmaxf(m, __shfl_xor(m, off));
    float s = 0.f;
#pragma unroll
    for (int t = 0; t < 16; ++t) s += __expf(v[t] - m);
#pragma unroll
    for (int off = 32; off > 0; off >>= 1) s += __shfl_xor(s, off);

    const float loss_std = m + __logf(s) - pos;

    // ---- radix select: value of the 512th-largest key, tie-exact ----
    u32 prefix = 0;
    u32 r = 512;
#pragma unroll
    for (int d = 3; d >= 0; --d) {
        *(uint4*)(h + lane * 4) = uint4{0u, 0u, 0u, 0u};
        __builtin_amdgcn_wave_barrier();
#pragma unroll
        for (int t = 0; t < 16; ++t) {
            bool act = true;
            if (d < 3) act = ((k[t] >> (8 * (d + 1))) == prefix);
            if (act) atomicAdd(&h[(k[t] >> (8 * d)) & 255u], 1u);
        }
        __builtin_amdgcn_wave_barrier();
        uint4 c = *(const uint4*)(h + lane * 4);
        u32 local = c.x + c.y + c.z + c.w;
        u32 S = local;
#pragma unroll
        for (int off = 1; off < 64; off <<= 1) {
            u32 tmp = __shfl_down(S, off);
            if (lane + off < 64) S += tmp;
        }
        const u32 above = S - local;
        const u32 cg3 = above + c.w;
        const u32 cg2 = cg3 + c.z;
        const u32 cg1 = cg2 + c.y;
        const u32 cg0 = cg1 + c.x;
        int q = -1;
        if      (cg3 >= r) q = 3;
        else if (cg2 >= r) q = 2;
        else if (cg1 >= r) q = 1;
        else if (cg0 >= r) q = 0;
        int cand = (q >= 0) ? (lane * 4 + q) : -1;
#pragma unroll
        for (int off = 32; off > 0; off >>= 1) cand = max(cand, __shfl_xor(cand, off));
        const u32 cgq = (q == 3) ? cg3 : (q == 2) ? cg2 : (q == 1) ? cg1 : cg0;
        const u32 cq  = (q == 3) ? c.w : (q == 2) ? c.z : (q == 1) ? c.y : c.x;
        const u32 rp_local = r - (cgq - cq);
        r = __shfl(rp_local, cand >> 2);
        prefix = (prefix << 8) | (u32)cand;
    }

    const u32 t_key = prefix;
    const float tval = key2f(t_key);

    // exact top-512 logsumexp using threshold + tie count
    float se = 0.f;
    int cgt = 0;
#pragma unroll
    for (int t = 0; t < 16; ++t) {
        if (k[t] > t_key) { se += __expf(v[t] - m); ++cgt; }
    }
#pragma unroll
    for (int off = 32; off > 0; off >>= 1) se += __shfl_xor(se, off);
#pragma unroll
    for (int off = 32; off > 0; off >>= 1) cgt += __shfl_xor(cgt, off);

    const float sh = se + (float)(512 - cgt) * __expf(tval - m) + __expf(pos - m);
    const float hard = m + __logf(sh) - pos;

    if (lane == 0)
        atomicAdd(out, (loss_std + 0.5f * hard) * (1.0f / 1024.0f));
}

// ---------------------------------------------------------------- launch
extern "C" void kernel_launch(void* const* d_in, const int* in_sizes, int n_in,
                              void* d_out, int out_size, void* d_ws, size_t ws_size,
                              hipStream_t stream) {
    const float* F    = (const float*)d_in[0];   // 1024*512
    const float* T    = (const float*)d_in[1];   // 1024*32*512
    const float* temp = (const float*)d_in[2];   // scalar
    float* out = (float*)d_out;

    char* ws = (char*)d_ws;
    u16*  Fb  = (u16*)ws;                                   // 1 MB
    u16*  Tb  = (u16*)(ws + (1u << 20));                    // 32 MB
    float* sim = (float*)(ws + (1u << 20) + (32u << 20));   // 4 MB

    hipMemsetAsync(d_out, 0, sizeof(float), stream);

    cvt_bf16<<<256, 256, 0, stream>>>(F, Fb, 1024 * 512);
    cvt_bf16<<<8192, 256, 0, stream>>>(T, Tb, 32768 * 512);

    dim3 grid(256, 8);
    gemm_max<<<grid, 256, 0, stream>>>(Fb, Tb, temp, sim);

    row_loss<<<1024 / 4, 256, 0, stream>>>(sim, out);
}

// Round 4
// 169.273 us; speedup vs baseline: 1.0247x; 1.0247x over previous
//
#include <hip/hip_runtime.h>
#include <hip/hip_bf16.h>
#include <math.h>

typedef unsigned short u16;
typedef unsigned int u32;
typedef __attribute__((ext_vector_type(4))) float f32x4;
typedef __attribute__((ext_vector_type(8))) __bf16 bf16x8;

// ---------------------------------------------------------------- fp32 -> bf16
__device__ __forceinline__ u16 f2bf(float x) {
    unsigned u = __float_as_uint(x);
    u += 0x7fffu + ((u >> 16) & 1u);   // round-to-nearest-even
    return (u16)(u >> 16);
}
__device__ __forceinline__ unsigned pk(float lo, float hi) {
    return (unsigned)f2bf(lo) | ((unsigned)f2bf(hi) << 16);
}

// One kernel: zero out[0], convert F (65536 chunks of 8) then T (2097152 chunks).
// Grid is exactly 65536+2097152 = 2162688 threads = 8448 blocks x 256.
__global__ void cvt_fused(const float* __restrict__ F, const float* __restrict__ T,
                          u16* __restrict__ Fb, u16* __restrict__ Tb,
                          float* __restrict__ out) {
    const int idx = blockIdx.x * blockDim.x + threadIdx.x;
    if (idx == 0) out[0] = 0.f;
    const float* s;
    u16* d;
    int i;
    if (idx < 65536) { s = F; d = Fb; i = idx * 8; }
    else             { s = T; d = Tb; i = (idx - 65536) * 8; }
    float4 v0 = *(const float4*)(s + i);
    float4 v1 = *(const float4*)(s + i + 4);
    uint4 o;
    o.x = pk(v0.x, v0.y); o.y = pk(v0.z, v0.w);
    o.z = pk(v1.x, v1.y); o.w = pk(v1.z, v1.w);
    *(uint4*)(d + i) = o;
}

// ---------------------------------------------------------------- GEMM + max
#define GLB_AS __attribute__((address_space(1)))
#define LDS_AS __attribute__((address_space(3)))

__device__ __forceinline__ void gload_lds16(const void* g, void* l) {
    __builtin_amdgcn_global_load_lds((const GLB_AS void*)g, (LDS_AS void*)l, 16, 0, 0);
}

// A: F bf16 [1024 x 512], B: T bf16 [32768 x 512] (row-major, K contiguous)
// sim[i*1024 + j] = max_{q<32} dot(A[i], B[j*32+q]) / temp
//
// BK=64. LDS layout per 128x64 tile: 16 "row-chunks" of 8 rows; within a
// row-chunk, slot l (16B) holds row (l>>3), k-chunk (l&7)^(l>>3)  [full XOR
// swizzle -> fragment ds_read_b128 hits all 32 banks at 2-way = free].
// Staging realizes the swizzle by choosing WHICH global 16B chunk lane l
// fetches (global_load_lds LDS slot is pinned to base + l*16).
__global__ __launch_bounds__(256, 2)
void gemm_max(const u16* __restrict__ A, const u16* __restrict__ B,
              const float* __restrict__ temp_ptr, float* __restrict__ sim) {
    __shared__ __align__(16) u16 lA[128 * 64];   // 16 KB
    __shared__ __align__(16) u16 lB[128 * 64];   // 16 KB
    const int bn = blockIdx.x;      // 0..255 (N tiles of 128 = 4 j's)
    const int bm = blockIdx.y;      // 0..7   (M tiles of 128)
    const int tid  = threadIdx.x;
    const int wave = tid >> 6;      // 0..3
    const int lane = tid & 63;
    const int wm = wave >> 1;       // 0..1
    const int wn = wave & 1;        // 0..1

    f32x4 acc[4][4] = {};

    // staging: one glds = 8 rows x 128B. lane l -> row l>>3, k-chunk (l&7)^(l>>3)
    const int srow = lane >> 3;                    // 0..7
    const int skc  = ((lane & 7) ^ srow) << 3;     // swizzled k elem offset
    const u16* gA0 = A + (size_t)(bm * 128 + wave * 8 + srow) * 512 + skc;
    const u16* gB0 = B + (size_t)(bn * 128 + wave * 8 + srow) * 512 + skc;
    u16* dA = lA + wave * 512;     // row-chunk (wave + 4j) at +j*2048 elems
    u16* dB = lB + wave * 512;

    // fragment read: row ra = wm*64 + t*16 + frow; elem addr =
    //   (ra>>3)*512 + (ra&7)*64 + ((c ^ (ra&7))<<3),  c = k-chunk = h*4 + fq
    const int frow  = lane & 15;
    const int fq    = lane >> 4;                   // k-quad 0..3
    const int abase = ((frow >> 3) * 512) + ((frow & 7) * 64);
    const int c0    = (fq ^ (frow & 7)) << 3;      // h=0 chunk; h=1 is c0 ^ 32

    for (int k0 = 0; k0 < 512; k0 += 64) {
#pragma unroll
        for (int j = 0; j < 4; ++j) {
            gload_lds16(gA0 + k0 + j * (32 * 512), dA + j * 2048);
            gload_lds16(gB0 + k0 + j * (32 * 512), dB + j * 2048);
        }
        __syncthreads();
#pragma unroll
        for (int h = 0; h < 2; ++h) {
            const int co = c0 ^ (h << 5);
            bf16x8 af[4], bf[4];
#pragma unroll
            for (int t = 0; t < 4; ++t) {
                af[t] = *(const bf16x8*)&lA[wm * 4096 + t * 1024 + abase + co];
                bf[t] = *(const bf16x8*)&lB[wn * 4096 + t * 1024 + abase + co];
            }
#pragma unroll
            for (int mt = 0; mt < 4; ++mt)
#pragma unroll
                for (int nt = 0; nt < 4; ++nt)
                    acc[mt][nt] = __builtin_amdgcn_mfma_f32_16x16x32_bf16(
                        af[mt], bf[nt], acc[mt][nt], 0, 0, 0);
        }
        __syncthreads();
    }

    // epilogue: C row = bm*128 + wm*64 + mt*16 + fq*4 + rr
    //           C col = bn*128 + wn*64 + nt*16 + (lane&15)
    const float tempv = *temp_ptr;
    const int jb = (bn * 128 + wn * 64) >> 5;
#pragma unroll
    for (int mt = 0; mt < 4; ++mt) {
#pragma unroll
        for (int rr = 0; rr < 4; ++rr) {
            float v0 = fmaxf(acc[mt][0][rr], acc[mt][1][rr]);
            float v1 = fmaxf(acc[mt][2][rr], acc[mt][3][rr]);
#pragma unroll
            for (int off = 1; off < 16; off <<= 1) {
                v0 = fmaxf(v0, __shfl_xor(v0, off));
                v1 = fmaxf(v1, __shfl_xor(v1, off));
            }
            if ((lane & 15) == 0) {
                const int row = bm * 128 + wm * 64 + mt * 16 + fq * 4 + rr;
                sim[row * 1024 + jb]     = v0 / tempv;
                sim[row * 1024 + jb + 1] = v1 / tempv;
            }
        }
    }
}

// ---------------------------------------------------------------- per-row loss
// ONE WAVE PER ROW, no __syncthreads. Row (1024 fp32) in 16 regs/lane.
__device__ __forceinline__ u32 f2key(float x) {
    u32 b = __float_as_uint(x);
    return (b & 0x80000000u) ? ~b : (b | 0x80000000u);
}
__device__ __forceinline__ float key2f(u32 k) {
    return __uint_as_float((k & 0x80000000u) ? (k & 0x7fffffffu) : ~k);
}

__global__ __launch_bounds__(256)
void row_loss(const float* __restrict__ sim, float* __restrict__ out) {
    __shared__ u32 hist[4 * 256];
    const int tid = threadIdx.x;
    const int lane = tid & 63;
    const int wv = tid >> 6;
    const int i = blockIdx.x * 4 + wv;          // row index
    u32* h = hist + wv * 256;

    // load row: slot t -> element (t>>2)*256 + lane*4 + (t&3)
    float v[16];
    const float4* rp = (const float4*)(sim + (size_t)i * 1024);
#pragma unroll
    for (int t = 0; t < 4; ++t) {
        float4 f = rp[t * 64 + lane];
        v[t * 4 + 0] = f.x; v[t * 4 + 1] = f.y; v[t * 4 + 2] = f.z; v[t * 4 + 3] = f.w;
    }

    const int dslot = ((i >> 8) << 2) | (i & 3);
    const int dlane = (i >> 2) & 63;

    // keys, diagonal masked to key 0 (below any finite key) — constant idx only
    u32 k[16];
#pragma unroll
    for (int t = 0; t < 16; ++t) {
        u32 kk = f2key(v[t]);
        k[t] = (lane == dlane && t == dslot) ? 0u : kk;
    }

    float pv = 0.f;
#pragma unroll
    for (int t = 0; t < 16; ++t) if (t == dslot) pv = v[t];
    const float pos = __shfl(pv, dlane);

    // full-row max + logsumexp (includes diagonal)
    float m = v[0];
#pragma unroll
    for (int t = 1; t < 16; ++t) m = fmaxf(m, v[t]);
#pragma unroll
    for (int off = 32; off > 0; off >>= 1) m = fmaxf(m, __shfl_xor(m, off));
    float s = 0.f;
#pragma unroll
    for (int t = 0; t < 16; ++t) s += __expf(v[t] - m);
#pragma unroll
    for (int off = 32; off > 0; off >>= 1) s += __shfl_xor(s, off);

    const float loss_std = m + __logf(s) - pos;

    // ---- radix select: value of the 512th-largest key, tie-exact ----
    u32 prefix = 0;
    u32 r = 512;
#pragma unroll
    for (int d = 3; d >= 0; --d) {
        *(uint4*)(h + lane * 4) = uint4{0u, 0u, 0u, 0u};
        __builtin_amdgcn_wave_barrier();
#pragma unroll
        for (int t = 0; t < 16; ++t) {
            bool act = true;
            if (d < 3) act = ((k[t] >> (8 * (d + 1))) == prefix);
            if (act) atomicAdd(&h[(k[t] >> (8 * d)) & 255u], 1u);
        }
        __builtin_amdgcn_wave_barrier();
        uint4 c = *(const uint4*)(h + lane * 4);
        u32 local = c.x + c.y + c.z + c.w;
        u32 S = local;
#pragma unroll
        for (int off = 1; off < 64; off <<= 1) {
            u32 tmp = __shfl_down(S, off);
            if (lane + off < 64) S += tmp;
        }
        const u32 above = S - local;
        const u32 cg3 = above + c.w;
        const u32 cg2 = cg3 + c.z;
        const u32 cg1 = cg2 + c.y;
        const u32 cg0 = cg1 + c.x;
        int q = -1;
        if      (cg3 >= r) q = 3;
        else if (cg2 >= r) q = 2;
        else if (cg1 >= r) q = 1;
        else if (cg0 >= r) q = 0;
        int cand = (q >= 0) ? (lane * 4 + q) : -1;
#pragma unroll
        for (int off = 32; off > 0; off >>= 1) cand = max(cand, __shfl_xor(cand, off));
        const u32 cgq = (q == 3) ? cg3 : (q == 2) ? cg2 : (q == 1) ? cg1 : cg0;
        const u32 cq  = (q == 3) ? c.w : (q == 2) ? c.z : (q == 1) ? c.y : c.x;
        const u32 rp_local = r - (cgq - cq);
        r = __shfl(rp_local, cand >> 2);
        prefix = (prefix << 8) | (u32)cand;
    }

    const u32 t_key = prefix;
    const float tval = key2f(t_key);

    // exact top-512 logsumexp using threshold + tie count
    float se = 0.f;
    int cgt = 0;
#pragma unroll
    for (int t = 0; t < 16; ++t) {
        if (k[t] > t_key) { se += __expf(v[t] - m); ++cgt; }
    }
#pragma unroll
    for (int off = 32; off > 0; off >>= 1) se += __shfl_xor(se, off);
#pragma unroll
    for (int off = 32; off > 0; off >>= 1) cgt += __shfl_xor(cgt, off);

    const float sh = se + (float)(512 - cgt) * __expf(tval - m) + __expf(pos - m);
    const float hard = m + __logf(sh) - pos;

    if (lane == 0)
        atomicAdd(out, (loss_std + 0.5f * hard) * (1.0f / 1024.0f));
}

// ---------------------------------------------------------------- launch
extern "C" void kernel_launch(void* const* d_in, const int* in_sizes, int n_in,
                              void* d_out, int out_size, void* d_ws, size_t ws_size,
                              hipStream_t stream) {
    const float* F    = (const float*)d_in[0];   // 1024*512
    const float* T    = (const float*)d_in[1];   // 1024*32*512
    const float* temp = (const float*)d_in[2];   // scalar
    float* out = (float*)d_out;

    char* ws = (char*)d_ws;
    u16*  Fb  = (u16*)ws;                                   // 1 MB
    u16*  Tb  = (u16*)(ws + (1u << 20));                    // 32 MB
    float* sim = (float*)(ws + (1u << 20) + (32u << 20));   // 4 MB

    cvt_fused<<<8448, 256, 0, stream>>>(F, T, Fb, Tb, out);

    dim3 grid(256, 8);
    gemm_max<<<grid, 256, 0, stream>>>(Fb, Tb, temp, sim);

    row_loss<<<256, 256, 0, stream>>>(sim, out);
}

// Round 5
// 162.281 us; speedup vs baseline: 1.0688x; 1.0431x over previous
//
#include <hip/hip_runtime.h>
#include <hip/hip_bf16.h>
#include <math.h>

typedef unsigned short u16;
typedef unsigned char u8;
typedef unsigned int u32;
typedef __attribute__((ext_vector_type(4))) float f32x4;
typedef __attribute__((ext_vector_type(8))) int i32x8;

// -------------------------------------------------- fp32 -> fp8 e4m3 (x16 pre-scale)
// l2-normed inputs: |x| <~ 0.3 -> x*16 in [~0.01, 4.8]: full mantissa, no saturation.
// Dequant is folded into the gemm epilogue (divide by 256*temp).
__global__ void cvt_fused(const float* __restrict__ F, const float* __restrict__ T,
                          u32* __restrict__ Fb, u32* __restrict__ Tb,
                          float* __restrict__ out) {
    const int idx = blockIdx.x * blockDim.x + threadIdx.x;
    if (idx == 0) out[0] = 0.f;
    const float* s;
    u32* d;
    int i;
    if (idx < 65536) { s = F; d = Fb; i = idx; }
    else             { s = T; d = Tb; i = idx - 65536; }
    const float4 v0 = *(const float4*)(s + (size_t)i * 8);
    const float4 v1 = *(const float4*)(s + (size_t)i * 8 + 4);
    int lo = __builtin_amdgcn_cvt_pk_fp8_f32(v0.x * 16.f, v0.y * 16.f, 0, false);
    lo     = __builtin_amdgcn_cvt_pk_fp8_f32(v0.z * 16.f, v0.w * 16.f, lo, true);
    int hi = __builtin_amdgcn_cvt_pk_fp8_f32(v1.x * 16.f, v1.y * 16.f, 0, false);
    hi     = __builtin_amdgcn_cvt_pk_fp8_f32(v1.z * 16.f, v1.w * 16.f, hi, true);
    uint2 o; o.x = (u32)lo; o.y = (u32)hi;
    ((uint2*)d)[i] = o;
}

// ---------------------------------------------------------------- GEMM + max
#define GLB_AS __attribute__((address_space(1)))
#define LDS_AS __attribute__((address_space(3)))

__device__ __forceinline__ void gload_lds16(const void* g, void* l) {
    __builtin_amdgcn_global_load_lds((const GLB_AS void*)g, (LDS_AS void*)l, 16, 0, 0);
}

// A: F fp8 [1024 x 512], B: T fp8 [32768 x 512] (row-major, K contiguous, bytes).
// sim[i*1024+j] = max_{q<32} dot(A[i],B[j*32+q]) / (256*temp)   (x16 pre-scale each side)
// BK=128 fp8: tile rows are 128 B — identical byte geometry to R4's proven layout.
// LDS: 16 row-groups of 8 rows; within a group, 16B slot s of row r holds global
// chunk s^r (full XOR swizzle -> ds_read_b128 conflict-free, verified R4).
__global__ __launch_bounds__(256, 2)
void gemm_max(const u8* __restrict__ A, const u8* __restrict__ B,
              const float* __restrict__ temp_ptr, float* __restrict__ sim) {
    __shared__ __align__(16) u8 lA[128 * 128];   // 16 KB
    __shared__ __align__(16) u8 lB[128 * 128];   // 16 KB
    const int bn = blockIdx.x;      // 0..255 (N tiles of 128 = 4 j's)
    const int bm = blockIdx.y;      // 0..7   (M tiles of 128)
    const int tid  = threadIdx.x;
    const int wave = tid >> 6;
    const int lane = tid & 63;
    const int wm = wave >> 1;
    const int wn = wave & 1;

    f32x4 acc[4][4] = {};

    // staging: wave w stages row-groups {w+4j}; one glds = 8 rows x 128B.
    const int srow = lane >> 3;                 // row within group
    const int sch  = (lane & 7) ^ srow;         // swizzled 16B chunk index
    const u8* gA0 = A + (size_t)(bm * 128 + wave * 8 + srow) * 512 + sch * 16;
    const u8* gB0 = B + (size_t)(bn * 128 + wave * 8 + srow) * 512 + sch * 16;
    u8* dA = lA + wave * 1024;
    u8* dB = lB + wave * 1024;

    // fragment: lane(frow=l&15, fq=l>>4) needs k-bytes [fq*32, fq*32+32) of its row
    // = chunks {2fq, 2fq+1}, each XOR'd with (row&7).
    const int frow = lane & 15;
    const int fq   = lane >> 4;

    union Frag { int4 h[2]; i32x8 v; };

    for (int k0 = 0; k0 < 512; k0 += 128) {
#pragma unroll
        for (int j = 0; j < 4; ++j) {           // groups w+4j; global rows 8w+32j+srow
            gload_lds16(gA0 + k0 + j * 16384, dA + j * 4096);
            gload_lds16(gB0 + k0 + j * 16384, dB + j * 4096);
        }
        __syncthreads();

        Frag af[4], bf[4];
#pragma unroll
        for (int t = 0; t < 4; ++t) {
            const int ra = wm * 64 + t * 16 + frow;
            const int ba = ((ra >> 3) << 10) + ((ra & 7) << 7);
            af[t].h[0] = *(const int4*)&lA[ba + ((((fq << 1))     ^ (ra & 7)) << 4)];
            af[t].h[1] = *(const int4*)&lA[ba + ((((fq << 1) | 1) ^ (ra & 7)) << 4)];
            const int rb = wn * 64 + t * 16 + frow;
            const int bb = ((rb >> 3) << 10) + ((rb & 7) << 7);
            bf[t].h[0] = *(const int4*)&lB[bb + ((((fq << 1))     ^ (rb & 7)) << 4)];
            bf[t].h[1] = *(const int4*)&lB[bb + ((((fq << 1) | 1) ^ (rb & 7)) << 4)];
        }
#pragma unroll
        for (int mt = 0; mt < 4; ++mt)
#pragma unroll
            for (int nt = 0; nt < 4; ++nt)
                acc[mt][nt] = __builtin_amdgcn_mfma_scale_f32_16x16x128_f8f6f4(
                    af[mt].v, bf[nt].v, acc[mt][nt],
                    0, 0,          // cbsz=fp8(e4m3), blgp=fp8(e4m3)
                    0, 0x7F,       // scale A: byte0, E8M0 127 = 1.0
                    0, 0x7F);      // scale B: 1.0
        __syncthreads();
    }

    // epilogue: C row = bm*128 + wm*64 + mt*16 + fq*4 + rr ; col = bn*128+wn*64+nt*16+(l&15)
    const float inv = 1.0f / (256.0f * (*temp_ptr));   // undo x16*x16 pre-scale, apply temp
    const int jb = (bn * 128 + wn * 64) >> 5;
#pragma unroll
    for (int mt = 0; mt < 4; ++mt) {
#pragma unroll
        for (int rr = 0; rr < 4; ++rr) {
            float v0 = fmaxf(acc[mt][0][rr], acc[mt][1][rr]);
            float v1 = fmaxf(acc[mt][2][rr], acc[mt][3][rr]);
#pragma unroll
            for (int off = 1; off < 16; off <<= 1) {
                v0 = fmaxf(v0, __shfl_xor(v0, off));
                v1 = fmaxf(v1, __shfl_xor(v1, off));
            }
            if ((lane & 15) == 0) {
                const int row = bm * 128 + wm * 64 + mt * 16 + fq * 4 + rr;
                sim[row * 1024 + jb]     = v0 * inv;
                sim[row * 1024 + jb + 1] = v1 * inv;
            }
        }
    }
}

// ---------------------------------------------------------------- per-row loss
// ONE WAVE PER ROW, zero LDS, zero barriers. Row (1024 fp32) in 16 regs/lane.
// 512th-largest off-diagonal found by 32-step binary search on monotone u32 keys
// (all-lane-uniform; exact under top_k tie semantics via threshold + tie count).
__device__ __forceinline__ u32 f2key(float x) {
    u32 b = __float_as_uint(x);
    return (b & 0x80000000u) ? ~b : (b | 0x80000000u);
}
__device__ __forceinline__ float key2f(u32 k) {
    return __uint_as_float((k & 0x80000000u) ? (k & 0x7fffffffu) : ~k);
}

__global__ __launch_bounds__(256)
void row_loss(const float* __restrict__ sim, float* __restrict__ out) {
    const int tid = threadIdx.x;
    const int lane = tid & 63;
    const int wv = tid >> 6;
    const int i = blockIdx.x * 4 + wv;          // row index

    // load row: slot t -> element (t>>2)*256 + lane*4 + (t&3)
    float v[16];
    const float4* rp = (const float4*)(sim + (size_t)i * 1024);
#pragma unroll
    for (int t = 0; t < 4; ++t) {
        float4 f = rp[t * 64 + lane];
        v[t * 4 + 0] = f.x; v[t * 4 + 1] = f.y; v[t * 4 + 2] = f.z; v[t * 4 + 3] = f.w;
    }

    const int dslot = ((i >> 8) << 2) | (i & 3);
    const int dlane = (i >> 2) & 63;

    u32 k[16];
#pragma unroll
    for (int t = 0; t < 16; ++t) {
        u32 kk = f2key(v[t]);
        k[t] = (lane == dlane && t == dslot) ? 0u : kk;   // diag -> below any finite key
    }

    float pv = 0.f;
#pragma unroll
    for (int t = 0; t < 16; ++t) if (t == dslot) pv = v[t];
    const float pos = __shfl(pv, dlane);

    // full-row max + logsumexp (includes diagonal)
    float m = v[0];
#pragma unroll
    for (int t = 1; t < 16; ++t) m = fmaxf(m, v[t]);
#pragma unroll
    for (int off = 32; off > 0; off >>= 1) m = fmaxf(m, __shfl_xor(m, off));
    float s = 0.f;
#pragma unroll
    for (int t = 0; t < 16; ++t) s += __expf(v[t] - m);
#pragma unroll
    for (int off = 32; off > 0; off >>= 1) s += __shfl_xor(s, off);
    const float loss_std = m + __logf(s) - pos;

    // binary search: largest x with count(key >= x) >= 512
    u32 lo = 0u, hi = 0xFFFFFFFFu;
    while (lo < hi) {
        const u32 span = hi - lo;
        const u32 mid = lo + (span >> 1) + (span & 1u);   // upper mid, no overflow
        int cnt = 0;
#pragma unroll
        for (int t = 0; t < 16; ++t) cnt += (k[t] >= mid);
#pragma unroll
        for (int off = 32; off > 0; off >>= 1) cnt += __shfl_xor(cnt, off);
        if (cnt >= 512) lo = mid; else hi = mid - 1;
    }
    const u32 t_key = lo;
    const float tval = key2f(t_key);

    // exact top-512 logsumexp: strict-greater sum + ties at threshold
    float se = 0.f;
    int cgt = 0;
#pragma unroll
    for (int t = 0; t < 16; ++t) {
        if (k[t] > t_key) { se += __expf(v[t] - m); ++cgt; }
    }
#pragma unroll
    for (int off = 32; off > 0; off >>= 1) se += __shfl_xor(se, off);
#pragma unroll
    for (int off = 32; off > 0; off >>= 1) cgt += __shfl_xor(cgt, off);

    const float sh = se + (float)(512 - cgt) * __expf(tval - m) + __expf(pos - m);
    const float hard = m + __logf(sh) - pos;

    if (lane == 0)
        atomicAdd(out, (loss_std + 0.5f * hard) * (1.0f / 1024.0f));
}

// ---------------------------------------------------------------- launch
extern "C" void kernel_launch(void* const* d_in, const int* in_sizes, int n_in,
                              void* d_out, int out_size, void* d_ws, size_t ws_size,
                              hipStream_t stream) {
    const float* F    = (const float*)d_in[0];   // 1024*512
    const float* T    = (const float*)d_in[1];   // 1024*32*512
    const float* temp = (const float*)d_in[2];   // scalar
    float* out = (float*)d_out;

    char* ws = (char*)d_ws;
    u32*  Fb8 = (u32*)ws;                                   // 0.5 MB fp8
    u32*  Tb8 = (u32*)(ws + (1u << 20));                    // 16 MB fp8
    float* sim = (float*)(ws + (1u << 20) + (32u << 20));   // 4 MB

    cvt_fused<<<8448, 256, 0, stream>>>(F, T, Fb8, Tb8, out);

    dim3 grid(256, 8);
    gemm_max<<<grid, 256, 0, stream>>>((const u8*)Fb8, (const u8*)Tb8, temp, sim);

    row_loss<<<256, 256, 0, stream>>>(sim, out);
}